// Round 16
// baseline (174.138 us; speedup 1.0000x reference)
//
#include <hip/hip_runtime.h>
#include <hip/hip_bf16.h>
#include <cstdint>

#define B_ 4
#define H_ 16
#define S_ 2048
#define D_ 1024
#define DK 64
// fold 1/sqrt(dk) and log2(e) into the Q projection -> scores in exp2 domain
#define QSCALE 0.18033688f

typedef float f32x4 __attribute__((ext_vector_type(4)));
typedef short bf8 __attribute__((ext_vector_type(8)));  // 8 bf16 = 16B
typedef unsigned short u16;

__device__ __forceinline__ u16 f2bf(float x){
  union { float f; uint32_t u; } c; c.f = x;
  uint32_t u = c.u;
  uint32_t r = (u + 0x7FFFu + ((u >> 16) & 1u)) >> 16;
  return (u16)r;
}

__device__ __forceinline__ uint32_t pk2bf(float a, float b){
  __hip_bfloat162 t = __float22bfloat162_rn(make_float2(a, b));
  uint32_t r; __builtin_memcpy(&r, &t, 4); return r;
}

// async global->LDS, 16B per lane. LDS dest = uniform base + lane*16.
__device__ __forceinline__ void gl16(const void* g, void* l){
  __builtin_amdgcn_global_load_lds(
      (const __attribute__((address_space(1))) void*)g,
      (__attribute__((address_space(3))) void*)l, 16, 0, 0);
}

// ------- fused prep: cvt_in (3072 blk) + wtrans3 (768 blk) + wtrans (256) ---
__global__ __launch_bounds__(256) void prep(
    const float* __restrict__ q, const float* __restrict__ k,
    const float* __restrict__ v, u16* __restrict__ o,
    const float* __restrict__ Wq, const float* __restrict__ Wk,
    const float* __restrict__ Wv, u16* __restrict__ oq,
    u16* __restrict__ ok, u16* __restrict__ ov,
    const float* __restrict__ Wo, u16* __restrict__ wto)
{
  __shared__ u16 T[64*72];
  const int bid = blockIdx.x;
  const int tid = threadIdx.x;
  if (bid < 3072){
    const size_t N8 = (size_t)1 << 20;
    const size_t tot = 3 * N8;
    const size_t step = (size_t)3072 * 256;
    for (size_t g0 = (size_t)bid*256 + tid; g0 < tot; g0 += step){
      int t = (int)(g0 >> 20);
      size_t r = g0 & (N8 - 1);
      const float* src = (t==0 ? q : (t==1 ? k : v));
      const float4* s4 = reinterpret_cast<const float4*>(src + r*8);
      float4 a = s4[0], b = s4[1];
      uint4 w;
      w.x = pk2bf(a.x,a.y); w.y = pk2bf(a.z,a.w);
      w.z = pk2bf(b.x,b.y); w.w = pk2bf(b.z,b.w);
      *reinterpret_cast<uint4*>(o + ((size_t)t << 23) + r*8) = w;
    }
  } else if (bid < 3072 + 768){
    const int idx = bid - 3072;
    const int z = idx >> 4, yb = idx & 15;
    const int t = z >> 4, hh = z & 15;
    const float* src = (t==0 ? Wq : t==1 ? Wk : Wv) + (size_t)hh * (D_*DK);
    u16* dst = (t==0 ? oq : t==1 ? ok : ov) + (size_t)hh * (DK*D_);
    const int r0 = yb*64;
    #pragma unroll
    for (int p=0;p<4;++p){
      int r  = p*16 + (tid>>4);
      int c4 = (tid&15)*4;
      float4 vv = *reinterpret_cast<const float4*>(&src[(size_t)(r0+r)*DK + c4]);
      uint2 w; w.x = pk2bf(vv.x, vv.y); w.y = pk2bf(vv.z, vv.w);
      *reinterpret_cast<uint2*>(&T[r*72 + c4]) = w;
    }
    __syncthreads();
    const int c = tid>>2, rg = (tid&3)*16;
    u16 tmp[16];
    #pragma unroll
    for (int i=0;i<16;++i) tmp[i] = T[(rg+i)*72 + c];
    *reinterpret_cast<bf8*>(&dst[(size_t)c*D_ + r0 + rg])     = *reinterpret_cast<bf8*>(&tmp[0]);
    *reinterpret_cast<bf8*>(&dst[(size_t)c*D_ + r0 + rg + 8]) = *reinterpret_cast<bf8*>(&tmp[8]);
  } else {
    const int idx = bid - 3840;
    const int c0 = (idx & 15)*64, r0 = (idx >> 4)*64;
    #pragma unroll
    for (int p=0;p<4;++p){
      int r  = p*16 + (tid>>4);
      int c4 = (tid&15)*4;
      float4 vv = *reinterpret_cast<const float4*>(&Wo[(size_t)(r0+r)*D_ + c0 + c4]);
      uint2 w; w.x = pk2bf(vv.x, vv.y); w.y = pk2bf(vv.z, vv.w);
      *reinterpret_cast<uint2*>(&T[r*72 + c4]) = w;
    }
    __syncthreads();
    const int c = tid>>2, rg = (tid&3)*16;
    u16 tmp[16];
    #pragma unroll
    for (int i=0;i<16;++i) tmp[i] = T[(rg+i)*72 + c];
    *reinterpret_cast<bf8*>(&wto[(size_t)(c0+c)*D_ + r0 + rg])     = *reinterpret_cast<bf8*>(&tmp[0]);
    *reinterpret_cast<bf8*>(&wto[(size_t)(c0+c)*D_ + r0 + rg + 8]) = *reinterpret_cast<bf8*>(&tmp[8]);
  }
}

// ------- fused Q/K/V projection GEMM: 128x128, BK=64, depth-2 counted vmcnt -
// Block decode remapped for L2 A-residency: z innermost with XCD-stride-8
// spacing (triples sharing (rb,cb) are adjacent & same XCD); cb slowest so a
// co-resident XCD cohort = all 8 rb panels (A 2MB, pinned) + ~3 cb panels.
__global__ __launch_bounds__(256) void gemm_qkv(
    const u16* __restrict__ Ab,
    const u16* __restrict__ Bq, const u16* __restrict__ Bk,
    const u16* __restrict__ Bv,
    const float* __restrict__ bq, const float* __restrict__ bk,
    const float* __restrict__ bv,
    u16* __restrict__ oq, u16* __restrict__ ok, u16* __restrict__ ov)
{
  __shared__ u16 As[2][128*64];
  __shared__ u16 Bs[2][128*64];
  const int tid = threadIdx.x;
  const int wid = tid>>6, lane = tid&63, g = lane>>4, l15 = lane&15;
  const int bid0 = blockIdx.x;           // 0..1535
  const int xcd = bid0 & 7;
  const int t0  = bid0 >> 3;             // 0..191
  const int z   = t0 % 3;
  const int i   = t0 / 3;                // 0..63
  const int cb  = i >> 3;                // 0..7  (slow)
  const int rb  = xcd*8 + (i & 7);       // 0..63
  const u16* A     = Ab + ((size_t)z << 23);
  const u16*   Bt  = (z==0 ? Bq : z==1 ? Bk : Bv);
  const float* bias= (z==0 ? bq : z==1 ? bk : bv);
  u16* Out         = (z==0 ? oq : z==1 ? ok : ov);
  const float osc  = (z==0 ? QSCALE : 1.0f);
  const int row0 = rb*128, col0 = cb*128;
  const int wr = wid>>1, wc = wid&1;

  f32x4 acc[4][4];
  #pragma unroll
  for (int m=0;m<4;++m)
    #pragma unroll
    for (int n=0;n<4;++n) acc[m][n] = (f32x4){0.f,0.f,0.f,0.f};

  auto STAGE = [&](int buf, int k0){
    #pragma unroll
    for (int p=0;p<4;++p){
      int r0l = wid*32 + p*8;
      int row = r0l + (lane>>3);
      int ch = (lane&7) ^ (row&7);
      gl16(A  + (size_t)(row0+row)*D_ + k0 + ch*8, &As[buf][r0l*64]);
      gl16(Bt + (size_t)(col0+row)*D_ + k0 + ch*8, &Bs[buf][r0l*64]);
    }
  };

  auto COMPUTE = [&](int cur){
    bf8 af[4][2], bfm[4][2];
    #pragma unroll
    for (int m=0;m<4;++m){
      int row = wr*64 + m*16 + l15;
      af[m][0] = *reinterpret_cast<const bf8*>(&As[cur][row*64 + ((g     ^(row&7))*8)]);
      af[m][1] = *reinterpret_cast<const bf8*>(&As[cur][row*64 + (((4+g) ^(row&7))*8)]);
    }
    #pragma unroll
    for (int n=0;n<4;++n){
      int row = wc*64 + n*16 + l15;
      bfm[n][0] = *reinterpret_cast<const bf8*>(&Bs[cur][row*64 + ((g     ^(row&7))*8)]);
      bfm[n][1] = *reinterpret_cast<const bf8*>(&Bs[cur][row*64 + (((4+g) ^(row&7))*8)]);
    }
    #pragma unroll
    for (int m=0;m<4;++m)
      #pragma unroll
      for (int n=0;n<4;++n){
        acc[m][n] = __builtin_amdgcn_mfma_f32_16x16x32_bf16(af[m][0], bfm[n][0], acc[m][n], 0,0,0);
        acc[m][n] = __builtin_amdgcn_mfma_f32_16x16x32_bf16(af[m][1], bfm[n][1], acc[m][n], 0,0,0);
      }
  };

  STAGE(0, 0);
  STAGE(1, 64);
  asm volatile("s_waitcnt vmcnt(8)" ::: "memory");
  asm volatile("s_barrier" ::: "memory");

  #pragma unroll 1
  for (int t = 0; t < 16; ++t){
    COMPUTE(t & 1);
    asm volatile("s_barrier" ::: "memory");
    if (t + 2 < 16){
      STAGE(t & 1, (t + 2) * 64);
      asm volatile("s_waitcnt vmcnt(8)" ::: "memory");
    } else {
      asm volatile("s_waitcnt vmcnt(0)" ::: "memory");
    }
    asm volatile("s_barrier" ::: "memory");
  }

  #pragma unroll
  for (int m=0;m<4;++m){
    #pragma unroll
    for (int n=0;n<4;++n){
      int col = col0 + wc*64 + n*16 + l15;
      float bs = bias[col];
      if (z == 2){
        int rowb = row0 + wr*64 + m*16 + g*4;
        int b = rowb>>11, s = rowb&2047;
        int h = col>>6, dkk = col&63;
        ushort4 pk;
        pk.x = f2bf(acc[m][n][0]+bs); pk.y = f2bf(acc[m][n][1]+bs);
        pk.z = f2bf(acc[m][n][2]+bs); pk.w = f2bf(acc[m][n][3]+bs);
        *reinterpret_cast<ushort4*>(&Out[(((size_t)(b*H_+h)*DK)+dkk)*S_ + s]) = pk;
      } else {
        #pragma unroll
        for (int r=0;r<4;++r){
          int row = row0 + wr*64 + m*16 + g*4 + r;
          float v = (acc[m][n][r] + bs)*osc;
          int b = row>>11, s = row&2047;
          int h = col>>6, dkk = col&63;
          Out[(((size_t)(b*H_+h)*S_)+s)*DK + dkk] = f2bf(v);
        }
      }
    }
  }
}

// ------- output GEMM: same depth-2 counted-vmcnt structure ------------------
__global__ __launch_bounds__(256) void gemm_out(
    const u16* __restrict__ A, const u16* __restrict__ Bt,
    const float* __restrict__ bias, float* __restrict__ Outp)
{
  __shared__ u16 As[2][128*64];
  __shared__ u16 Bs[2][128*64];
  const int tid = threadIdx.x;
  const int wid = tid>>6, lane = tid&63, g = lane>>4, l15 = lane&15;
  const int bid = blockIdx.x;
  const int xcd = bid & 7, i = bid >> 3;
  const int cb = i & 7, rb = xcd*8 + (i>>3);
  const int row0 = rb*128, col0 = cb*128;
  const int wr = wid>>1, wc = wid&1;

  f32x4 acc[4][4];
  #pragma unroll
  for (int m=0;m<4;++m)
    #pragma unroll
    for (int n=0;n<4;++n) acc[m][n] = (f32x4){0.f,0.f,0.f,0.f};

  auto STAGE = [&](int buf, int k0){
    #pragma unroll
    for (int p=0;p<4;++p){
      int r0l = wid*32 + p*8;
      int row = r0l + (lane>>3);
      int ch = (lane&7) ^ (row&7);
      gl16(A  + (size_t)(row0+row)*D_ + k0 + ch*8, &As[buf][r0l*64]);
      gl16(Bt + (size_t)(col0+row)*D_ + k0 + ch*8, &Bs[buf][r0l*64]);
    }
  };

  auto COMPUTE = [&](int cur){
    bf8 af[4][2], bfm[4][2];
    #pragma unroll
    for (int m=0;m<4;++m){
      int row = wr*64 + m*16 + l15;
      af[m][0] = *reinterpret_cast<const bf8*>(&As[cur][row*64 + ((g     ^(row&7))*8)]);
      af[m][1] = *reinterpret_cast<const bf8*>(&As[cur][row*64 + (((4+g) ^(row&7))*8)]);
    }
    #pragma unroll
    for (int n=0;n<4;++n){
      int row = wc*64 + n*16 + l15;
      bfm[n][0] = *reinterpret_cast<const bf8*>(&Bs[cur][row*64 + ((g     ^(row&7))*8)]);
      bfm[n][1] = *reinterpret_cast<const bf8*>(&Bs[cur][row*64 + (((4+g) ^(row&7))*8)]);
    }
    #pragma unroll
    for (int m=0;m<4;++m)
      #pragma unroll
      for (int n=0;n<4;++n){
        acc[m][n] = __builtin_amdgcn_mfma_f32_16x16x32_bf16(af[m][0], bfm[n][0], acc[m][n], 0,0,0);
        acc[m][n] = __builtin_amdgcn_mfma_f32_16x16x32_bf16(af[m][1], bfm[n][1], acc[m][n], 0,0,0);
      }
  };

  STAGE(0, 0);
  STAGE(1, 64);
  asm volatile("s_waitcnt vmcnt(8)" ::: "memory");
  asm volatile("s_barrier" ::: "memory");

  #pragma unroll 1
  for (int t = 0; t < 16; ++t){
    COMPUTE(t & 1);
    asm volatile("s_barrier" ::: "memory");
    if (t + 2 < 16){
      STAGE(t & 1, (t + 2) * 64);
      asm volatile("s_waitcnt vmcnt(8)" ::: "memory");
    } else {
      asm volatile("s_waitcnt vmcnt(0)" ::: "memory");
    }
    asm volatile("s_barrier" ::: "memory");
  }

  #pragma unroll
  for (int m=0;m<4;++m){
    #pragma unroll
    for (int n=0;n<4;++n){
      int col = col0 + wc*64 + n*16 + l15;
      float bs = bias[col];
      #pragma unroll
      for (int r=0;r<4;++r){
        int row = row0 + wr*64 + m*16 + g*4 + r;
        Outp[(size_t)row*D_ + col] = acc[m][n][r] + bs;
      }
    }
  }
}

// ------- flash attention: swapped QK^T -> packed b64 P-writes ---------------
__global__ __launch_bounds__(256) void attn_kernel(
    const u16* __restrict__ qp, const u16* __restrict__ kp,
    const u16* __restrict__ vt, u16* __restrict__ ctx)
{
  __shared__ u16 Kl[2][64*64];
  __shared__ u16 Vl[2][64*64];
  __shared__ u16 Pl[4][32*72];
  const int tid = threadIdx.x;
  const int wid = tid>>6, lane = tid&63, g = lane>>4, l15 = lane&15;
  const int bid0 = blockIdx.x;
  const int xx = bid0 & 7, yy = bid0 >> 3;
  const int bh = xx + 8*(yy & 7);
  const int qt = 15 - (yy >> 3);     // longest first
  const int b = bh >> 4, h = bh & 15;
  const size_t base = (size_t)bh * S_ * DK;

  bf8 ones;
  #pragma unroll
  for (int i=0;i<8;++i) ones[i] = (short)0x3F80;

  const int Q0 = qt*128;
  bf8 aq[2][2];
  #pragma unroll
  for (int qs=0;qs<2;++qs){
    int qrow = Q0 + wid*32 + qs*16 + l15;
    aq[qs][0] = *reinterpret_cast<const bf8*>(&qp[base + (size_t)qrow*DK +      g*8]);
    aq[qs][1] = *reinterpret_cast<const bf8*>(&qp[base + (size_t)qrow*DK + 32 + g*8]);
  }

  f32x4 acco[2][4], acc_l[2];
  #pragma unroll
  for (int qs=0;qs<2;++qs){
    #pragma unroll
    for (int nd=0;nd<4;++nd) acco[qs][nd] = (f32x4){0.f,0.f,0.f,0.f};
    acc_l[qs] = (f32x4){0.f,0.f,0.f,0.f};
  }

  auto STAGE = [&](int buf, int kt){
    const int k0 = kt*64;
    #pragma unroll
    for (int p=0;p<2;++p){
      int r0l = wid*16 + p*8;
      int row = r0l + (lane>>3);
      int ch  = (lane&7) ^ (row&7);
      gl16(kp + base + (size_t)(k0+row)*DK + ch*8, &Kl[buf][r0l*64]);
      gl16(vt + base + (size_t)row*S_ + k0 + ch*8, &Vl[buf][r0l*64]);
    }
  };

  const int nk = 2*qt + 2;
  int cur = 0;
  STAGE(cur, 0);
  asm volatile("s_waitcnt vmcnt(0)" ::: "memory");
  __syncthreads();

  for (int kt = 0; kt < nk; ++kt){
    if (kt < nk-1) STAGE(cur^1, kt+1);   // prefetch next tile (async)

    // swapped scores: sc[qs][n][r] = S[q=l15][k = n*16+g*4+r] (exp2 domain)
    f32x4 sc[2][4];
    __builtin_amdgcn_s_setprio(1);
    #pragma unroll
    for (int n=0;n<4;++n){
      int row = n*16 + l15;
      bf8 b0 = *reinterpret_cast<const bf8*>(&Kl[cur][row*64 + ((g     ^(row&7))*8)]);
      bf8 b1 = *reinterpret_cast<const bf8*>(&Kl[cur][row*64 + (((4+g) ^(row&7))*8)]);
      #pragma unroll
      for (int qs=0;qs<2;++qs){
        f32x4 z = (f32x4){0.f,0.f,0.f,0.f};
        z = __builtin_amdgcn_mfma_f32_16x16x32_bf16(b0, aq[qs][0], z, 0,0,0);
        z = __builtin_amdgcn_mfma_f32_16x16x32_bf16(b1, aq[qs][1], z, 0,0,0);
        sc[qs][n] = z;
      }
    }
    __builtin_amdgcn_s_setprio(0);
    if (kt >= nk-2){  // diagonal region: causal mask (swapped indexing)
      const int k0 = kt*64;
      #pragma unroll
      for (int qs=0;qs<2;++qs){
        int qg = Q0 + wid*32 + qs*16 + l15;
        #pragma unroll
        for (int n=0;n<4;++n){
          #pragma unroll
          for (int r=0;r<4;++r){
            int kg = k0 + n*16 + g*4 + r;
            if (kg > qg) sc[qs][n][r] = -1e30f;
          }
        }
      }
    }
    // P = exp2(s); pack 4 contiguous-k values -> one b64 write per (qs,n)
    #pragma unroll
    for (int qs=0;qs<2;++qs){
      #pragma unroll
      for (int n=0;n<4;++n){
        uint2 w;
        w.x = pk2bf(__builtin_amdgcn_exp2f(sc[qs][n][0]),
                    __builtin_amdgcn_exp2f(sc[qs][n][1]));
        w.y = pk2bf(__builtin_amdgcn_exp2f(sc[qs][n][2]),
                    __builtin_amdgcn_exp2f(sc[qs][n][3]));
        *reinterpret_cast<uint2*>(&Pl[wid][(qs*16 + l15)*72 + n*16 + g*4]) = w;
      }
    }
    // P is wave-private: wave-level wait, reads pinned below the fence
    asm volatile("s_waitcnt lgkmcnt(0)" ::: "memory");
    __builtin_amdgcn_sched_barrier(0);

    bf8 pa[2][2];
    __builtin_amdgcn_s_setprio(1);
    #pragma unroll
    for (int qs=0;qs<2;++qs){
      pa[qs][0] = *reinterpret_cast<const bf8*>(&Pl[wid][(qs*16 + l15)*72 +      g*8]);
      pa[qs][1] = *reinterpret_cast<const bf8*>(&Pl[wid][(qs*16 + l15)*72 + 32 + g*8]);
      acc_l[qs] = __builtin_amdgcn_mfma_f32_16x16x32_bf16(pa[qs][0], ones, acc_l[qs], 0,0,0);
      acc_l[qs] = __builtin_amdgcn_mfma_f32_16x16x32_bf16(pa[qs][1], ones, acc_l[qs], 0,0,0);
    }
    #pragma unroll
    for (int nd=0;nd<4;++nd){
      int row = nd*16 + l15;
      bf8 v0 = *reinterpret_cast<const bf8*>(&Vl[cur][row*64 + ((g     ^(row&7))*8)]);
      bf8 v1 = *reinterpret_cast<const bf8*>(&Vl[cur][row*64 + (((4+g) ^(row&7))*8)]);
      #pragma unroll
      for (int qs=0;qs<2;++qs){
        acco[qs][nd] = __builtin_amdgcn_mfma_f32_16x16x32_bf16(pa[qs][0], v0, acco[qs][nd], 0,0,0);
        acco[qs][nd] = __builtin_amdgcn_mfma_f32_16x16x32_bf16(pa[qs][1], v1, acco[qs][nd], 0,0,0);
      }
    }
    __builtin_amdgcn_s_setprio(0);
    asm volatile("s_waitcnt vmcnt(0)" ::: "memory");  // prefetch landed
    __syncthreads();
    cur ^= 1;
  }

  // epilogue
  #pragma unroll
  for (int qs=0;qs<2;++qs){
    float rl[4];
    #pragma unroll
    for (int r=0;r<4;++r) rl[r] = __builtin_amdgcn_rcpf(acc_l[qs][r]);
    #pragma unroll
    for (int nd=0;nd<4;++nd){
      #pragma unroll
      for (int r=0;r<4;++r){
        int qg = Q0 + wid*32 + qs*16 + g*4 + r;
        float v = acco[qs][nd][r] * rl[r];
        ctx[((size_t)(b*S_) + qg)*D_ + h*DK + nd*16 + l15] = f2bf(v);
      }
    }
  }
}

extern "C" void kernel_launch(void* const* d_in, const int* in_sizes, int n_in,
                              void* d_out, int out_size, void* d_ws, size_t ws_size,
                              hipStream_t stream)
{
  const float* values  = (const float*)d_in[0];
  const float* queries = (const float*)d_in[1];
  const float* keys    = (const float*)d_in[2];
  const float* Wq = (const float*)d_in[3];
  const float* bq = (const float*)d_in[4];
  const float* Wk = (const float*)d_in[5];
  const float* bk = (const float*)d_in[6];
  const float* Wv = (const float*)d_in[7];
  const float* bv = (const float*)d_in[8];
  const float* Wo = (const float*)d_in[9];
  const float* bo = (const float*)d_in[10];
  float* out = (float*)d_out;

  const size_t NE = (size_t)B_*H_*S_*DK;   // 8.39M elems per tensor
  const size_t WE = (size_t)D_*D_;
  u16* cvt = (u16*)d_ws;                   // [3][8192][1024] bf16 (q,k,v inputs)
  u16* qp  = cvt + 3*NE;
  u16* kp  = qp + NE;
  u16* vtb = kp + NE;
  u16* wtq = vtb + NE;
  u16* wtk = wtq + WE;
  u16* wtv = wtk + WE;
  u16* wto = wtv + WE;
  u16* ctx = cvt;                          // cvt region dead after gemm_qkv

  prep<<<4096, 256, 0, stream>>>(queries, keys, values, cvt,
                                 Wq, Wk, Wv, wtq, wtk, wtv, Wo, wto);
  gemm_qkv<<<1536, 256, 0, stream>>>(cvt, wtq, wtk, wtv,
                                     bq, bk, bv, qp, kp, vtb);
  attn_kernel<<<1024, 256, 0, stream>>>(qp, kp, vtb, ctx);
  gemm_out<<<512, 256, 0, stream>>>(ctx, wto, bo, out);
}

// Round 17
// 169.728 us; speedup vs baseline: 1.0260x; 1.0260x over previous
//
#include <hip/hip_runtime.h>
#include <hip/hip_bf16.h>
#include <cstdint>

#define B_ 4
#define H_ 16
#define S_ 2048
#define D_ 1024
#define DK 64
// fold 1/sqrt(dk) and log2(e) into the Q projection -> scores in exp2 domain
#define QSCALE 0.18033688f

typedef float f32x4 __attribute__((ext_vector_type(4)));
typedef short bf8 __attribute__((ext_vector_type(8)));  // 8 bf16 = 16B
typedef unsigned short u16;

__device__ __forceinline__ u16 f2bf(float x){
  union { float f; uint32_t u; } c; c.f = x;
  uint32_t u = c.u;
  uint32_t r = (u + 0x7FFFu + ((u >> 16) & 1u)) >> 16;
  return (u16)r;
}

__device__ __forceinline__ uint32_t pk2bf(float a, float b){
  __hip_bfloat162 t = __float22bfloat162_rn(make_float2(a, b));
  uint32_t r; __builtin_memcpy(&r, &t, 4); return r;
}

// async global->LDS, 16B per lane. LDS dest = uniform base + lane*16.
__device__ __forceinline__ void gl16(const void* g, void* l){
  __builtin_amdgcn_global_load_lds(
      (const __attribute__((address_space(1))) void*)g,
      (__attribute__((address_space(3))) void*)l, 16, 0, 0);
}

// ------- fused prep: cvt_in (3072 blk) + wtrans3 (768 blk) + wtrans (256) ---
__global__ __launch_bounds__(256) void prep(
    const float* __restrict__ q, const float* __restrict__ k,
    const float* __restrict__ v, u16* __restrict__ o,
    const float* __restrict__ Wq, const float* __restrict__ Wk,
    const float* __restrict__ Wv, u16* __restrict__ oq,
    u16* __restrict__ ok, u16* __restrict__ ov,
    const float* __restrict__ Wo, u16* __restrict__ wto)
{
  __shared__ u16 T[64*72];
  const int bid = blockIdx.x;
  const int tid = threadIdx.x;
  if (bid < 3072){
    const size_t N8 = (size_t)1 << 20;
    const size_t tot = 3 * N8;
    const size_t step = (size_t)3072 * 256;
    for (size_t g0 = (size_t)bid*256 + tid; g0 < tot; g0 += step){
      int t = (int)(g0 >> 20);
      size_t r = g0 & (N8 - 1);
      const float* src = (t==0 ? q : (t==1 ? k : v));
      const float4* s4 = reinterpret_cast<const float4*>(src + r*8);
      float4 a = s4[0], b = s4[1];
      uint4 w;
      w.x = pk2bf(a.x,a.y); w.y = pk2bf(a.z,a.w);
      w.z = pk2bf(b.x,b.y); w.w = pk2bf(b.z,b.w);
      *reinterpret_cast<uint4*>(o + ((size_t)t << 23) + r*8) = w;
    }
  } else if (bid < 3072 + 768){
    const int idx = bid - 3072;
    const int z = idx >> 4, yb = idx & 15;
    const int t = z >> 4, hh = z & 15;
    const float* src = (t==0 ? Wq : t==1 ? Wk : Wv) + (size_t)hh * (D_*DK);
    u16* dst = (t==0 ? oq : t==1 ? ok : ov) + (size_t)hh * (DK*D_);
    const int r0 = yb*64;
    #pragma unroll
    for (int p=0;p<4;++p){
      int r  = p*16 + (tid>>4);
      int c4 = (tid&15)*4;
      float4 vv = *reinterpret_cast<const float4*>(&src[(size_t)(r0+r)*DK + c4]);
      uint2 w; w.x = pk2bf(vv.x, vv.y); w.y = pk2bf(vv.z, vv.w);
      *reinterpret_cast<uint2*>(&T[r*72 + c4]) = w;
    }
    __syncthreads();
    const int c = tid>>2, rg = (tid&3)*16;
    u16 tmp[16];
    #pragma unroll
    for (int i=0;i<16;++i) tmp[i] = T[(rg+i)*72 + c];
    *reinterpret_cast<bf8*>(&dst[(size_t)c*D_ + r0 + rg])     = *reinterpret_cast<bf8*>(&tmp[0]);
    *reinterpret_cast<bf8*>(&dst[(size_t)c*D_ + r0 + rg + 8]) = *reinterpret_cast<bf8*>(&tmp[8]);
  } else {
    const int idx = bid - 3840;
    const int c0 = (idx & 15)*64, r0 = (idx >> 4)*64;
    #pragma unroll
    for (int p=0;p<4;++p){
      int r  = p*16 + (tid>>4);
      int c4 = (tid&15)*4;
      float4 vv = *reinterpret_cast<const float4*>(&Wo[(size_t)(r0+r)*D_ + c0 + c4]);
      uint2 w; w.x = pk2bf(vv.x, vv.y); w.y = pk2bf(vv.z, vv.w);
      *reinterpret_cast<uint2*>(&T[r*72 + c4]) = w;
    }
    __syncthreads();
    const int c = tid>>2, rg = (tid&3)*16;
    u16 tmp[16];
    #pragma unroll
    for (int i=0;i<16;++i) tmp[i] = T[(rg+i)*72 + c];
    *reinterpret_cast<bf8*>(&wto[(size_t)(c0+c)*D_ + r0 + rg])     = *reinterpret_cast<bf8*>(&tmp[0]);
    *reinterpret_cast<bf8*>(&wto[(size_t)(c0+c)*D_ + r0 + rg + 8]) = *reinterpret_cast<bf8*>(&tmp[8]);
  }
}

// ------- fused Q/K/V projection GEMM: 128x128, BK=64, depth-2 counted vmcnt -
__global__ __launch_bounds__(256) void gemm_qkv(
    const u16* __restrict__ Ab,
    const u16* __restrict__ Bq, const u16* __restrict__ Bk,
    const u16* __restrict__ Bv,
    const float* __restrict__ bq, const float* __restrict__ bk,
    const float* __restrict__ bv,
    u16* __restrict__ oq, u16* __restrict__ ok, u16* __restrict__ ov)
{
  __shared__ u16 As[2][128*64];
  __shared__ u16 Bs[2][128*64];
  const int tid = threadIdx.x;
  const int wid = tid>>6, lane = tid&63, g = lane>>4, l15 = lane&15;
  const int z = blockIdx.x >> 9, bid = blockIdx.x & 511;
  const u16* A     = Ab + ((size_t)z << 23);
  const u16*   Bt  = (z==0 ? Bq : z==1 ? Bk : Bv);
  const float* bias= (z==0 ? bq : z==1 ? bk : bv);
  u16* Out         = (z==0 ? oq : z==1 ? ok : ov);
  const float osc  = (z==0 ? QSCALE : 1.0f);
  const int xcd = bid & 7, i = bid >> 3;
  const int cb = i & 7, rb = xcd*8 + (i>>3);
  const int row0 = rb*128, col0 = cb*128;
  const int wr = wid>>1, wc = wid&1;

  f32x4 acc[4][4];
  #pragma unroll
  for (int m=0;m<4;++m)
    #pragma unroll
    for (int n=0;n<4;++n) acc[m][n] = (f32x4){0.f,0.f,0.f,0.f};

  auto STAGE = [&](int buf, int k0){
    #pragma unroll
    for (int p=0;p<4;++p){
      int r0l = wid*32 + p*8;
      int row = r0l + (lane>>3);
      int ch = (lane&7) ^ (row&7);
      gl16(A  + (size_t)(row0+row)*D_ + k0 + ch*8, &As[buf][r0l*64]);
      gl16(Bt + (size_t)(col0+row)*D_ + k0 + ch*8, &Bs[buf][r0l*64]);
    }
  };

  auto COMPUTE = [&](int cur){
    bf8 af[4][2], bfm[4][2];
    #pragma unroll
    for (int m=0;m<4;++m){
      int row = wr*64 + m*16 + l15;
      af[m][0] = *reinterpret_cast<const bf8*>(&As[cur][row*64 + ((g     ^(row&7))*8)]);
      af[m][1] = *reinterpret_cast<const bf8*>(&As[cur][row*64 + (((4+g) ^(row&7))*8)]);
    }
    #pragma unroll
    for (int n=0;n<4;++n){
      int row = wc*64 + n*16 + l15;
      bfm[n][0] = *reinterpret_cast<const bf8*>(&Bs[cur][row*64 + ((g     ^(row&7))*8)]);
      bfm[n][1] = *reinterpret_cast<const bf8*>(&Bs[cur][row*64 + (((4+g) ^(row&7))*8)]);
    }
    #pragma unroll
    for (int m=0;m<4;++m)
      #pragma unroll
      for (int n=0;n<4;++n){
        acc[m][n] = __builtin_amdgcn_mfma_f32_16x16x32_bf16(af[m][0], bfm[n][0], acc[m][n], 0,0,0);
        acc[m][n] = __builtin_amdgcn_mfma_f32_16x16x32_bf16(af[m][1], bfm[n][1], acc[m][n], 0,0,0);
      }
  };

  STAGE(0, 0);
  STAGE(1, 64);
  asm volatile("s_waitcnt vmcnt(8)" ::: "memory");
  asm volatile("s_barrier" ::: "memory");

  #pragma unroll 1
  for (int t = 0; t < 16; ++t){
    COMPUTE(t & 1);
    asm volatile("s_barrier" ::: "memory");
    if (t + 2 < 16){
      STAGE(t & 1, (t + 2) * 64);
      asm volatile("s_waitcnt vmcnt(8)" ::: "memory");
    } else {
      asm volatile("s_waitcnt vmcnt(0)" ::: "memory");
    }
    asm volatile("s_barrier" ::: "memory");
  }

  #pragma unroll
  for (int m=0;m<4;++m){
    #pragma unroll
    for (int n=0;n<4;++n){
      int col = col0 + wc*64 + n*16 + l15;
      float bs = bias[col];
      if (z == 2){
        int rowb = row0 + wr*64 + m*16 + g*4;
        int b = rowb>>11, s = rowb&2047;
        int h = col>>6, dkk = col&63;
        ushort4 pk;
        pk.x = f2bf(acc[m][n][0]+bs); pk.y = f2bf(acc[m][n][1]+bs);
        pk.z = f2bf(acc[m][n][2]+bs); pk.w = f2bf(acc[m][n][3]+bs);
        *reinterpret_cast<ushort4*>(&Out[(((size_t)(b*H_+h)*DK)+dkk)*S_ + s]) = pk;
      } else {
        #pragma unroll
        for (int r=0;r<4;++r){
          int row = row0 + wr*64 + m*16 + g*4 + r;
          float v = (acc[m][n][r] + bs)*osc;
          int b = row>>11, s = row&2047;
          int h = col>>6, dkk = col&63;
          Out[(((size_t)(b*H_+h)*S_)+s)*DK + dkk] = f2bf(v);
        }
      }
    }
  }
}

// ------- output GEMM: same depth-2 counted-vmcnt structure ------------------
__global__ __launch_bounds__(256) void gemm_out(
    const u16* __restrict__ A, const u16* __restrict__ Bt,
    const float* __restrict__ bias, float* __restrict__ Outp)
{
  __shared__ u16 As[2][128*64];
  __shared__ u16 Bs[2][128*64];
  const int tid = threadIdx.x;
  const int wid = tid>>6, lane = tid&63, g = lane>>4, l15 = lane&15;
  const int bid = blockIdx.x;
  const int xcd = bid & 7, i = bid >> 3;
  const int cb = i & 7, rb = xcd*8 + (i>>3);
  const int row0 = rb*128, col0 = cb*128;
  const int wr = wid>>1, wc = wid&1;

  f32x4 acc[4][4];
  #pragma unroll
  for (int m=0;m<4;++m)
    #pragma unroll
    for (int n=0;n<4;++n) acc[m][n] = (f32x4){0.f,0.f,0.f,0.f};

  auto STAGE = [&](int buf, int k0){
    #pragma unroll
    for (int p=0;p<4;++p){
      int r0l = wid*32 + p*8;
      int row = r0l + (lane>>3);
      int ch = (lane&7) ^ (row&7);
      gl16(A  + (size_t)(row0+row)*D_ + k0 + ch*8, &As[buf][r0l*64]);
      gl16(Bt + (size_t)(col0+row)*D_ + k0 + ch*8, &Bs[buf][r0l*64]);
    }
  };

  auto COMPUTE = [&](int cur){
    bf8 af[4][2], bfm[4][2];
    #pragma unroll
    for (int m=0;m<4;++m){
      int row = wr*64 + m*16 + l15;
      af[m][0] = *reinterpret_cast<const bf8*>(&As[cur][row*64 + ((g     ^(row&7))*8)]);
      af[m][1] = *reinterpret_cast<const bf8*>(&As[cur][row*64 + (((4+g) ^(row&7))*8)]);
    }
    #pragma unroll
    for (int n=0;n<4;++n){
      int row = wc*64 + n*16 + l15;
      bfm[n][0] = *reinterpret_cast<const bf8*>(&Bs[cur][row*64 + ((g     ^(row&7))*8)]);
      bfm[n][1] = *reinterpret_cast<const bf8*>(&Bs[cur][row*64 + (((4+g) ^(row&7))*8)]);
    }
    #pragma unroll
    for (int m=0;m<4;++m)
      #pragma unroll
      for (int n=0;n<4;++n){
        acc[m][n] = __builtin_amdgcn_mfma_f32_16x16x32_bf16(af[m][0], bfm[n][0], acc[m][n], 0,0,0);
        acc[m][n] = __builtin_amdgcn_mfma_f32_16x16x32_bf16(af[m][1], bfm[n][1], acc[m][n], 0,0,0);
      }
  };

  STAGE(0, 0);
  STAGE(1, 64);
  asm volatile("s_waitcnt vmcnt(8)" ::: "memory");
  asm volatile("s_barrier" ::: "memory");

  #pragma unroll 1
  for (int t = 0; t < 16; ++t){
    COMPUTE(t & 1);
    asm volatile("s_barrier" ::: "memory");
    if (t + 2 < 16){
      STAGE(t & 1, (t + 2) * 64);
      asm volatile("s_waitcnt vmcnt(8)" ::: "memory");
    } else {
      asm volatile("s_waitcnt vmcnt(0)" ::: "memory");
    }
    asm volatile("s_barrier" ::: "memory");
  }

  #pragma unroll
  for (int m=0;m<4;++m){
    #pragma unroll
    for (int n=0;n<4;++n){
      int col = col0 + wc*64 + n*16 + l15;
      float bs = bias[col];
      #pragma unroll
      for (int r=0;r<4;++r){
        int row = row0 + wr*64 + m*16 + g*4 + r;
        Outp[(size_t)row*D_ + col] = acc[m][n][r] + bs;
      }
    }
  }
}

// ------- flash attention: swapped QK^T -> packed b64 P-writes ---------------
__global__ __launch_bounds__(256) void attn_kernel(
    const u16* __restrict__ qp, const u16* __restrict__ kp,
    const u16* __restrict__ vt, u16* __restrict__ ctx)
{
  __shared__ u16 Kl[2][64*64];
  __shared__ u16 Vl[2][64*64];
  __shared__ u16 Pl[4][32*72];
  const int tid = threadIdx.x;
  const int wid = tid>>6, lane = tid&63, g = lane>>4, l15 = lane&15;
  const int bid0 = blockIdx.x;
  const int xx = bid0 & 7, yy = bid0 >> 3;
  const int bh = xx + 8*(yy & 7);
  const int qt = 15 - (yy >> 3);     // longest first
  const int b = bh >> 4, h = bh & 15;
  const size_t base = (size_t)bh * S_ * DK;

  bf8 ones;
  #pragma unroll
  for (int i=0;i<8;++i) ones[i] = (short)0x3F80;

  const int Q0 = qt*128;
  bf8 aq[2][2];
  #pragma unroll
  for (int qs=0;qs<2;++qs){
    int qrow = Q0 + wid*32 + qs*16 + l15;
    aq[qs][0] = *reinterpret_cast<const bf8*>(&qp[base + (size_t)qrow*DK +      g*8]);
    aq[qs][1] = *reinterpret_cast<const bf8*>(&qp[base + (size_t)qrow*DK + 32 + g*8]);
  }

  f32x4 acco[2][4], acc_l[2];
  #pragma unroll
  for (int qs=0;qs<2;++qs){
    #pragma unroll
    for (int nd=0;nd<4;++nd) acco[qs][nd] = (f32x4){0.f,0.f,0.f,0.f};
    acc_l[qs] = (f32x4){0.f,0.f,0.f,0.f};
  }

  auto STAGE = [&](int buf, int kt){
    const int k0 = kt*64;
    #pragma unroll
    for (int p=0;p<2;++p){
      int r0l = wid*16 + p*8;
      int row = r0l + (lane>>3);
      int ch  = (lane&7) ^ (row&7);
      gl16(kp + base + (size_t)(k0+row)*DK + ch*8, &Kl[buf][r0l*64]);
      gl16(vt + base + (size_t)row*S_ + k0 + ch*8, &Vl[buf][r0l*64]);
    }
  };

  const int nk = 2*qt + 2;
  int cur = 0;
  STAGE(cur, 0);
  asm volatile("s_waitcnt vmcnt(0)" ::: "memory");
  __syncthreads();

  for (int kt = 0; kt < nk; ++kt){
    if (kt < nk-1) STAGE(cur^1, kt+1);   // prefetch next tile (async)

    // swapped scores: sc[qs][n][r] = S[q=l15][k = n*16+g*4+r] (exp2 domain)
    f32x4 sc[2][4];
    __builtin_amdgcn_s_setprio(1);
    #pragma unroll
    for (int n=0;n<4;++n){
      int row = n*16 + l15;
      bf8 b0 = *reinterpret_cast<const bf8*>(&Kl[cur][row*64 + ((g     ^(row&7))*8)]);
      bf8 b1 = *reinterpret_cast<const bf8*>(&Kl[cur][row*64 + (((4+g) ^(row&7))*8)]);
      #pragma unroll
      for (int qs=0;qs<2;++qs){
        f32x4 z = (f32x4){0.f,0.f,0.f,0.f};
        z = __builtin_amdgcn_mfma_f32_16x16x32_bf16(b0, aq[qs][0], z, 0,0,0);
        z = __builtin_amdgcn_mfma_f32_16x16x32_bf16(b1, aq[qs][1], z, 0,0,0);
        sc[qs][n] = z;
      }
    }
    __builtin_amdgcn_s_setprio(0);
    if (kt >= nk-2){  // diagonal region: causal mask (swapped indexing)
      const int k0 = kt*64;
      #pragma unroll
      for (int qs=0;qs<2;++qs){
        int qg = Q0 + wid*32 + qs*16 + l15;
        #pragma unroll
        for (int n=0;n<4;++n){
          #pragma unroll
          for (int r=0;r<4;++r){
            int kg = k0 + n*16 + g*4 + r;
            if (kg > qg) sc[qs][n][r] = -1e30f;
          }
        }
      }
    }
    // P = exp2(s); pack 4 contiguous-k values -> one b64 write per (qs,n)
    #pragma unroll
    for (int qs=0;qs<2;++qs){
      #pragma unroll
      for (int n=0;n<4;++n){
        uint2 w;
        w.x = pk2bf(__builtin_amdgcn_exp2f(sc[qs][n][0]),
                    __builtin_amdgcn_exp2f(sc[qs][n][1]));
        w.y = pk2bf(__builtin_amdgcn_exp2f(sc[qs][n][2]),
                    __builtin_amdgcn_exp2f(sc[qs][n][3]));
        *reinterpret_cast<uint2*>(&Pl[wid][(qs*16 + l15)*72 + n*16 + g*4]) = w;
      }
    }
    // P is wave-private: wave-level wait, reads pinned below the fence
    asm volatile("s_waitcnt lgkmcnt(0)" ::: "memory");
    __builtin_amdgcn_sched_barrier(0);

    bf8 pa[2][2];
    __builtin_amdgcn_s_setprio(1);
    #pragma unroll
    for (int qs=0;qs<2;++qs){
      pa[qs][0] = *reinterpret_cast<const bf8*>(&Pl[wid][(qs*16 + l15)*72 +      g*8]);
      pa[qs][1] = *reinterpret_cast<const bf8*>(&Pl[wid][(qs*16 + l15)*72 + 32 + g*8]);
      acc_l[qs] = __builtin_amdgcn_mfma_f32_16x16x32_bf16(pa[qs][0], ones, acc_l[qs], 0,0,0);
      acc_l[qs] = __builtin_amdgcn_mfma_f32_16x16x32_bf16(pa[qs][1], ones, acc_l[qs], 0,0,0);
    }
    #pragma unroll
    for (int nd=0;nd<4;++nd){
      int row = nd*16 + l15;
      bf8 v0 = *reinterpret_cast<const bf8*>(&Vl[cur][row*64 + ((g     ^(row&7))*8)]);
      bf8 v1 = *reinterpret_cast<const bf8*>(&Vl[cur][row*64 + (((4+g) ^(row&7))*8)]);
      #pragma unroll
      for (int qs=0;qs<2;++qs){
        acco[qs][nd] = __builtin_amdgcn_mfma_f32_16x16x32_bf16(pa[qs][0], v0, acco[qs][nd], 0,0,0);
        acco[qs][nd] = __builtin_amdgcn_mfma_f32_16x16x32_bf16(pa[qs][1], v1, acco[qs][nd], 0,0,0);
      }
    }
    __builtin_amdgcn_s_setprio(0);
    asm volatile("s_waitcnt vmcnt(0)" ::: "memory");  // prefetch landed
    __syncthreads();
    cur ^= 1;
  }

  // epilogue
  #pragma unroll
  for (int qs=0;qs<2;++qs){
    float rl[4];
    #pragma unroll
    for (int r=0;r<4;++r) rl[r] = __builtin_amdgcn_rcpf(acc_l[qs][r]);
    #pragma unroll
    for (int nd=0;nd<4;++nd){
      #pragma unroll
      for (int r=0;r<4;++r){
        int qg = Q0 + wid*32 + qs*16 + g*4 + r;
        float v = acco[qs][nd][r] * rl[r];
        ctx[((size_t)(b*S_) + qg)*D_ + h*DK + nd*16 + l15] = f2bf(v);
      }
    }
  }
}

extern "C" void kernel_launch(void* const* d_in, const int* in_sizes, int n_in,
                              void* d_out, int out_size, void* d_ws, size_t ws_size,
                              hipStream_t stream)
{
  const float* values  = (const float*)d_in[0];
  const float* queries = (const float*)d_in[1];
  const float* keys    = (const float*)d_in[2];
  const float* Wq = (const float*)d_in[3];
  const float* bq = (const float*)d_in[4];
  const float* Wk = (const float*)d_in[5];
  const float* bk = (const float*)d_in[6];
  const float* Wv = (const float*)d_in[7];
  const float* bv = (const float*)d_in[8];
  const float* Wo = (const float*)d_in[9];
  const float* bo = (const float*)d_in[10];
  float* out = (float*)d_out;

  const size_t NE = (size_t)B_*H_*S_*DK;   // 8.39M elems per tensor
  const size_t WE = (size_t)D_*D_;
  u16* cvt = (u16*)d_ws;                   // [3][8192][1024] bf16 (q,k,v inputs)
  u16* qp  = cvt + 3*NE;
  u16* kp  = qp + NE;
  u16* vtb = kp + NE;
  u16* wtq = vtb + NE;
  u16* wtk = wtq + WE;
  u16* wtv = wtk + WE;
  u16* wto = wtv + WE;
  u16* ctx = cvt;                          // cvt region dead after gemm_qkv

  prep<<<4096, 256, 0, stream>>>(queries, keys, values, cvt,
                                 Wq, Wk, Wv, wtq, wtk, wtv, Wo, wto);
  gemm_qkv<<<1536, 256, 0, stream>>>(cvt, wtq, wtk, wtv,
                                     bq, bk, bv, qp, kp, vtb);
  attn_kernel<<<1024, 256, 0, stream>>>(qp, kp, vtb, ctx);
  gemm_out<<<512, 256, 0, stream>>>(ctx, wto, bo, out);
}